// Round 1
// 362.258 us; speedup vs baseline: 1.0427x; 1.0427x over previous
//
#include <hip/hip_runtime.h>

#define B 2
#define N_RES 2048
#define N_ATOM 16384
#define C_S 384
#define C_OUT 50

#define PROJ_BLOCKS 1024                  // 4 waves/block × 1024 = 4096 = B*N_RES residues
#define NROWS (B * N_ATOM)                // 32768 one-hot rows (one per atom)
#define SCAN_WAVES (NROWS / 2)            // 2 rows per wave (dual-stream latency hiding)
#define SCAN_BLOCKS (SCAN_WAVES / 4)      // 4096 blocks of 4 waves
#define NCHUNK (N_RES / 256)              // 8 chunks of 256 floats (64 lanes × float4)

typedef float nfloat4 __attribute__((ext_vector_type(4)));

// Blocks [0, PROJ_BLOCKS): proj[b,r,o] = bias[o] + s[b,r,:]·W[o,:]  (L2-bound).
// Blocks [PROJ_BLOCKS, +SCAN_BLOCKS): EARLY-EXIT one-hot scan. Each wave owns two
// rows; per row it reads 256-float chunks (float4/lane, NT) sequentially and stops
// at the first nonzero (exactly one per row, uniform position -> E[traffic]=56.25%
// of the row instead of 100%). Two independent streams per wave keep 2 KiB of HBM
// reads in flight per wave (8192 resident waves ≈ 16 MiB outstanding ≫ BW·latency),
// so the scan stays HBM-BW-bound despite the dependent chunk chain.
__global__ __launch_bounds__(256) void fused_scan_proj(const float* __restrict__ s,
                                                       const float* __restrict__ W,
                                                       const float* __restrict__ bias,
                                                       const float* __restrict__ onehot,
                                                       float* __restrict__ proj,
                                                       int* __restrict__ idx) {
    __shared__ float srow[4][C_S];
    int wave = threadIdx.x >> 6;
    int lane = threadIdx.x & 63;

    if (blockIdx.x >= PROJ_BLOCKS) {
        // -------- early-exit streaming scan: 2 rows per wave --------
        int w  = ((blockIdx.x - PROJ_BLOCKS) << 2) + wave;   // wave id
        int a0 = w << 1;                                     // first row (atom)
        int a1 = a0 | 1;                                     // second row
        const nfloat4* r0 = (const nfloat4*)(onehot + (size_t)a0 * N_RES) + lane;
        const nfloat4* r1 = r0 + (N_RES / 4);                // next row, same lane
        int  c0 = 0, c1 = 0;                                 // chunk cursors (uniform)
        bool d0 = false, d1 = false;                         // done flags (uniform)
        for (int it = 0; it < NCHUNK && !(d0 && d1); ++it) {
            nfloat4 v0, v1;
            if (!d0) v0 = __builtin_nontemporal_load(r0 + (c0 << 6));
            if (!d1) v1 = __builtin_nontemporal_load(r1 + (c1 << 6));
            if (!d0) {
                bool nz = (v0.x != 0.f) || (v0.y != 0.f) || (v0.z != 0.f) || (v0.w != 0.f);
                if (nz) {   // at most one lane per row hits: unguarded single store
                    int j = (v0.x != 0.f) ? 0 : (v0.y != 0.f) ? 1 : (v0.z != 0.f) ? 2 : 3;
                    idx[a0] = (c0 << 8) + (lane << 2) + j;   // residue index r
                }
                if (__any(nz)) d0 = true; else ++c0;
            }
            if (!d1) {
                bool nz = (v1.x != 0.f) || (v1.y != 0.f) || (v1.z != 0.f) || (v1.w != 0.f);
                if (nz) {
                    int j = (v1.x != 0.f) ? 0 : (v1.y != 0.f) ? 1 : (v1.z != 0.f) ? 2 : 3;
                    idx[a1] = (c1 << 8) + (lane << 2) + j;
                }
                if (__any(nz)) d1 = true; else ++c1;
            }
        }
    } else {
        // -------- projection: one wave per residue --------
        int rr = (blockIdx.x << 2) + wave;                 // 0 .. B*N_RES-1
        const float4* sp = (const float4*)(s + (size_t)rr * C_S);
        float4* srp = (float4*)srow[wave];
        for (int i = lane; i < C_S / 4; i += 64) srp[i] = sp[i];
        __syncthreads();   // branch is block-uniform: all 256 threads reach this
        if (lane < C_OUT) {
            const float* wp = W + lane * C_S;
            float acc = bias[lane];
            #pragma unroll 4
            for (int c = 0; c < C_S; c += 4) {
                float4 w4 = *(const float4*)(wp + c);
                acc += srow[wave][c]     * w4.x + srow[wave][c + 1] * w4.y
                     + srow[wave][c + 2] * w4.z + srow[wave][c + 3] * w4.w;
            }
            proj[(size_t)rr * C_OUT + lane] = acc;
        }
    }
}

// K2: one wave per atom: out[a, :] = proj[b, idx[a], :]  (proj is L2-hot)
__global__ __launch_bounds__(256) void gather_kernel(const int* __restrict__ idx,
                                                     const float* __restrict__ proj,
                                                     float* __restrict__ out) {
    int wave = threadIdx.x >> 6;
    int lane = threadIdx.x & 63;
    int a = (blockIdx.x << 2) + wave;                  // 0 .. B*N_ATOM-1
    int r = idx[a];                                    // broadcast load
    int b = a >> 14;                                   // / N_ATOM
    if (lane < C_OUT) {
        out[(size_t)a * C_OUT + lane] = proj[((size_t)b * N_RES + r) * C_OUT + lane];
    }
}

extern "C" void kernel_launch(void* const* d_in, const int* in_sizes, int n_in,
                              void* d_out, int out_size, void* d_ws, size_t ws_size,
                              hipStream_t stream) {
    const float* s      = (const float*)d_in[0];   // [B, N_RES, C_S]
    const float* onehot = (const float*)d_in[1];   // [B, N_ATOM, N_RES]
    const float* W      = (const float*)d_in[2];   // [C_OUT, C_S]
    const float* bias   = (const float*)d_in[3];   // [C_OUT]
    float* out  = (float*)d_out;                   // [B, N_ATOM, C_OUT]

    float* proj = (float*)d_ws;                            // 819200 B
    int*   idx  = (int*)((char*)d_ws + (1 << 20));         // 128 KiB at 1 MiB offset

    fused_scan_proj<<<PROJ_BLOCKS + SCAN_BLOCKS, 256, 0, stream>>>(s, W, bias, onehot,
                                                                   proj, idx);
    gather_kernel<<<(B * N_ATOM) / 4, 256, 0, stream>>>(idx, proj, out);
}